// Round 1
// baseline (208.111 us; speedup 1.0000x reference)
//
#include <hip/hip_runtime.h>

typedef unsigned short u16;
typedef __attribute__((ext_vector_type(8))) short bf16x8;   // 8 bf16 (4 VGPRs)
typedef __attribute__((ext_vector_type(4))) float f32x4;    // MFMA C/D frag

#define MTOK 8192   // B*N tokens
#define KP   640    // K padded (588 -> 640 = 10*64)
#define CC   588
#define C3   1764
#define NH   14
#define SEQ  1024
#define HD   42
#define DP   64     // head-dim padded for QK^T K-loop
#define DV   48     // V^T rows: 42 real + ones row (42) + zeros

static __device__ __forceinline__ u16 f2b(float f) {  // fp32 -> bf16 RNE
  unsigned u = __builtin_bit_cast(unsigned, f);
  u = (u + 0x7FFFu + ((u >> 16) & 1u)) >> 16;
  return (u16)u;
}

static __device__ __forceinline__ void gl_lds16(const void* g, void* l) {
  // async global->LDS, 16B/lane; LDS dst is wave-uniform base + lane*16
  auto gp = (const unsigned int __attribute__((address_space(1)))*)((unsigned long long)g);
  auto lp = (unsigned int __attribute__((address_space(3)))*)((unsigned long long)l);
  __builtin_amdgcn_global_load_lds(gp, lp, 16, 0, 0);
}

// ---------------- im2col: x [8,3,448,448] f32 -> A [8192][640] bf16 (zero-padded) ----------------
__global__ void im2col_k(const float* __restrict__ x, u16* __restrict__ A) {
  int t = blockIdx.x;
  int b = t >> 10, pi = t & 1023, ph = pi >> 5, pw = pi & 31;
  const float* xb = x + (size_t)b * 3 * 448 * 448;
  for (int kk = threadIdx.x; kk < KP; kk += 256) {
    float v = 0.f;
    if (kk < CC) {
      int c = kk / 196, rem = kk - c * 196, i = rem / 14, j = rem - i * 14;
      v = xb[(size_t)(c * 448 + ph * 14 + i) * 448 + pw * 14 + j];
    }
    A[(size_t)t * KP + kk] = f2b(v);
  }
}

// ---------------- weight pad/convert: [R][588] f32 -> [Rp][640] bf16 (zeros elsewhere) ----------------
__global__ void padw_k(const float* __restrict__ w, u16* __restrict__ dst, int R) {
  int r = blockIdx.x;
  for (int c = threadIdx.x; c < KP; c += 256) {
    float v = (r < R && c < CC) ? w[(size_t)r * CC + c] : 0.f;
    dst[(size_t)r * KP + c] = f2b(v);
  }
}

// ---------------- 128x128x(BK=64) bf16 MFMA GEMM, C = A * Bt^T ----------------
// MODE 0: tokens epilogue (+conv bias, bf16 out, stride KP)
// MODE 1: qkv epilogue (+qkv bias, scatter to q/k/v [b,h,n,64] bf16)
template <int MODE>
__global__ void __launch_bounds__(256, 2) gemm_k(
    const u16* __restrict__ A, const u16* __restrict__ Bt,
    const float* __restrict__ bias, u16* __restrict__ out0,
    u16* __restrict__ qb, u16* __restrict__ kb, u16* __restrict__ vb) {
  __shared__ alignas(16) u16 sA[128 * 64];
  __shared__ alignas(16) u16 sB[128 * 64];
  const int tid = threadIdx.x;
  const int wave = tid >> 6, lane = tid & 63, quad = lane >> 4, l16 = lane & 15;
  const int wi = wave >> 1, wj = wave & 1;
  const int m0 = blockIdx.x * 128, n0 = blockIdx.y * 128;
  const int rL = lane >> 3, scid = lane & 7;
  const f32x4 z4 = {0.f, 0.f, 0.f, 0.f};

  f32x4 acc[4][4];
#pragma unroll
  for (int i = 0; i < 4; i++)
#pragma unroll
    for (int j = 0; j < 4; j++) acc[i][j] = z4;

  for (int k0 = 0; k0 < KP; k0 += 64) {
    __syncthreads();
    // stage A,B tiles [128][64] with XOR swizzle: LDS slot (r, sc) <- global chunk (sc ^ (r&7))
#pragma unroll
    for (int cc = wave; cc < 16; cc += 4) {
      int r = cc * 8 + rL;
      int sch = scid ^ (r & 7);
      gl_lds16(A + ((size_t)(m0 + r) * KP + k0 + sch * 8), &sA[cc * 512]);
    }
#pragma unroll
    for (int cc = wave; cc < 16; cc += 4) {
      int r = cc * 8 + rL;
      int sch = scid ^ (r & 7);
      gl_lds16(Bt + ((size_t)(n0 + r) * KP + k0 + sch * 8), &sB[cc * 512]);
    }
    __syncthreads();
#pragma unroll
    for (int ks = 0; ks < 2; ks++) {
      bf16x8 af[4], bfr[4];
#pragma unroll
      for (int i = 0; i < 4; i++) {
        int r = wi * 64 + i * 16 + l16;
        int ch = (ks * 4 + quad) ^ (r & 7);
        af[i] = *(const bf16x8*)&sA[r * 64 + ch * 8];
      }
#pragma unroll
      for (int j = 0; j < 4; j++) {
        int r = wj * 64 + j * 16 + l16;
        int ch = (ks * 4 + quad) ^ (r & 7);
        bfr[j] = *(const bf16x8*)&sB[r * 64 + ch * 8];
      }
#pragma unroll
      for (int i = 0; i < 4; i++)
#pragma unroll
        for (int j = 0; j < 4; j++)
          acc[i][j] = __builtin_amdgcn_mfma_f32_16x16x32_bf16(af[i], bfr[j], acc[i][j], 0, 0, 0);
    }
  }

  const int baser = wi * 64 + quad * 4;  // C/D: col = lane&15, row = quad*4 + reg
  if (MODE == 0) {
#pragma unroll
    for (int j = 0; j < 4; j++) {
      int col = n0 + wj * 64 + j * 16 + l16;
      float bs = (col < CC) ? bias[col] : 0.f;
#pragma unroll
      for (int i = 0; i < 4; i++) {
        int row = m0 + baser + i * 16;
#pragma unroll
        for (int r = 0; r < 4; r++)
          out0[(size_t)(row + r) * KP + col] = f2b(acc[i][j][r] + bs);
      }
    }
  } else {
#pragma unroll
    for (int j = 0; j < 4; j++) {
      int col = n0 + wj * 64 + j * 16 + l16;
      if (col < C3) {
        float bs = bias[col];
        int which = col / CC;
        int rem = col - which * CC;
        int h = rem / HD;
        int d = rem - h * HD;
        u16* dst = (which == 0) ? qb : (which == 1) ? kb : vb;
#pragma unroll
        for (int i = 0; i < 4; i++) {
          int row = m0 + baser + i * 16;
#pragma unroll
          for (int r = 0; r < 4; r++) {
            int rw = row + r;
            int b = rw >> 10, n = rw & 1023;
            dst[((size_t)((b * NH + h) * SEQ + n)) * DP + d] = f2b(acc[i][j][r] + bs);
          }
        }
      }
    }
  }
}

// ---------------- V transpose: v [bh][n][64] -> vT [bh][48][1024]; row 42 = ones, 43..47 = 0 ----------------
__global__ void vtrans_k(const u16* __restrict__ vb, u16* __restrict__ vT) {
  __shared__ u16 tile[64 * 49];
  int bh = blockIdx.x, mt = blockIdx.y;
  for (int idx = threadIdx.x; idx < 64 * DV; idx += 256) {
    int n = idx / DV, d = idx - n * DV;
    u16 v = 0;
    if (d < HD) v = vb[((size_t)(bh * SEQ + mt * 64 + n)) * DP + d];
    tile[n * 49 + d] = v;
  }
  __syncthreads();
  for (int idx = threadIdx.x; idx < DV * 64; idx += 256) {
    int d = idx >> 6, n = idx & 63;
    u16 v = (d < HD) ? tile[n * 49 + d] : ((d == HD) ? (u16)0x3F80 : (u16)0);
    vT[((size_t)(bh * DV + d)) * SEQ + mt * 64 + n] = v;
  }
}

// ---------------- attention: per block one (b,h) x 64 Q rows; flash over 16 KV tiles ----------------
__global__ void __launch_bounds__(256, 2) attn_k(
    const u16* __restrict__ qb, const u16* __restrict__ kb,
    const u16* __restrict__ vT, float* __restrict__ out) {
  __shared__ alignas(16) u16 sK[64 * 64];   // swizzled
  __shared__ alignas(16) u16 sV[DV * 64];   // swizzled V^T tile
  __shared__ alignas(16) u16 sP[64 * 72];   // P round-trip, stride 72 elems (144B, 16B-aligned, conflict-free)
  const int tid = threadIdx.x;
  const int wave = tid >> 6, lane = tid & 63, quad = lane >> 4, l16 = lane & 15;
  const int bh = blockIdx.x >> 4, qt = blockIdx.x & 15;
  const int q0 = qt * 64;
  const int rL = lane >> 3, scid = lane & 7;
  const float SC2 = 0.18033688011112042f;  // 0.125 * log2(e): softmax(s*c) via exp2
  const f32x4 z4 = {0.f, 0.f, 0.f, 0.f};

  bf16x8 aq0, aq1;  // Q A-frags, resident all kernel (wave owns q rows wave*16..+15)
  {
    const u16* qrow = qb + ((size_t)(bh * SEQ + q0 + wave * 16 + l16)) * DP;
    aq0 = *(const bf16x8*)&qrow[quad * 8];
    aq1 = *(const bf16x8*)&qrow[32 + quad * 8];
  }
  f32x4 o[3] = {z4, z4, z4};  // 16x48 accum; col 42 accumulates row-sum l (ones column of V^T)
  const u16* kb0 = kb + (size_t)bh * SEQ * DP;
  const u16* vb0 = vT + (size_t)bh * DV * SEQ;

  for (int kt = 0; kt < 16; kt++) {
    const int m0 = kt * 64;
    __syncthreads();
    {
      const u16* ktile = kb0 + (size_t)m0 * DP;  // contiguous 8KB
#pragma unroll
      for (int cc = wave; cc < 8; cc += 4) {
        int r = cc * 8 + rL;
        int sch = scid ^ (r & 7);
        gl_lds16(ktile + ((size_t)r * 64 + sch * 8), &sK[cc * 512]);
      }
      for (int cc = wave; cc < 6; cc += 4) {
        int d = cc * 8 + rL;
        int sch = scid ^ (d & 7);
        gl_lds16(vb0 + ((size_t)d * SEQ + m0 + sch * 8), &sV[cc * 512]);
      }
    }
    __syncthreads();
    // S = Q K^T (K=64 padded), P = exp2(S*c) -> LDS in A-layout rows
#pragma unroll
    for (int j = 0; j < 4; j++) {
      f32x4 s = z4;
#pragma unroll
      for (int ks = 0; ks < 2; ks++) {
        int n = j * 16 + l16;
        int ch = (ks * 4 + quad) ^ (n & 7);
        bf16x8 bk = *(const bf16x8*)&sK[n * 64 + ch * 8];
        s = __builtin_amdgcn_mfma_f32_16x16x32_bf16(ks == 0 ? aq0 : aq1, bk, s, 0, 0, 0);
      }
#pragma unroll
      for (int r = 0; r < 4; r++) {
        float p = __builtin_amdgcn_exp2f(s[r] * SC2);
        sP[(wave * 16 + quad * 4 + r) * 72 + j * 16 + l16] = f2b(p);
      }
    }
    __syncthreads();
    // O += P V (K-dim = 64 keys)
#pragma unroll
    for (int ks = 0; ks < 2; ks++) {
      bf16x8 ap = *(const bf16x8*)&sP[(wave * 16 + l16) * 72 + ks * 32 + quad * 8];
#pragma unroll
      for (int j = 0; j < 3; j++) {
        int d = j * 16 + l16;
        int ch = (ks * 4 + quad) ^ (d & 7);
        bf16x8 bv = *(const bf16x8*)&sV[d * 64 + ch * 8];
        o[j] = __builtin_amdgcn_mfma_f32_16x16x32_bf16(ap, bv, o[j], 0, 0, 0);
      }
    }
  }
  // epilogue: broadcast per-row l (col 42 -> j=2, l16==10) via LDS, normalize, store fp32
  __syncthreads();
  float* lsum = (float*)sP;
  if (l16 == 10) {
#pragma unroll
    for (int r = 0; r < 4; r++) lsum[wave * 16 + quad * 4 + r] = o[2][r];
  }
  __syncthreads();
  const int b = bh / NH, h = bh - b * NH;
#pragma unroll
  for (int r = 0; r < 4; r++) {
    int row = wave * 16 + quad * 4 + r;
    float rc = 1.f / lsum[row];
    float* orow = out + ((size_t)(b * SEQ + q0 + row)) * CC + h * HD;
#pragma unroll
    for (int j = 0; j < 3; j++) {
      int d = j * 16 + l16;
      if (d < HD) orow[d] = o[j][r] * rc;
    }
  }
}

extern "C" void kernel_launch(void* const* d_in, const int* in_sizes, int n_in,
                              void* d_out, int out_size, void* d_ws, size_t ws_size,
                              hipStream_t stream) {
  (void)in_sizes; (void)n_in; (void)out_size; (void)ws_size;
  const float* x      = (const float*)d_in[0];
  const float* conv_w = (const float*)d_in[1];
  const float* conv_b = (const float*)d_in[2];
  const float* qkv_w  = (const float*)d_in[3];
  const float* qkv_b  = (const float*)d_in[4];
  float* out = (float*)d_out;

  char* ws = (char*)d_ws;
  size_t off = 0;
  u16* A      = (u16*)(ws + off); off += (size_t)MTOK * KP * 2;      // 10.5 MB
  u16* Wc     = (u16*)(ws + off); off += (size_t)640 * KP * 2;       // 0.8 MB
  u16* Wq     = (u16*)(ws + off); off += (size_t)1792 * KP * 2;      // 2.3 MB
  u16* tokens = (u16*)(ws + off); off += (size_t)MTOK * KP * 2;      // 10.5 MB
  u16* qbuf   = (u16*)(ws + off); off += (size_t)112 * SEQ * DP * 2; // 14.7 MB
  u16* kbuf   = (u16*)(ws + off); off += (size_t)112 * SEQ * DP * 2; // 14.7 MB
  u16* vbuf   = (u16*)(ws + off); off += (size_t)112 * SEQ * DP * 2; // 14.7 MB
  u16* vTb    = (u16*)(ws + off); off += (size_t)112 * DV * SEQ * 2; // 11.0 MB
  // total ~79.1 MB

  // zero q/k/v (d-pad 42..63 must be 0 for the K=64 QK^T loop)
  hipMemsetAsync(qbuf, 0, (size_t)3 * 112 * SEQ * DP * 2, stream);
  im2col_k<<<MTOK, 256, 0, stream>>>(x, A);
  padw_k<<<640, 256, 0, stream>>>(conv_w, Wc, CC);
  padw_k<<<1792, 256, 0, stream>>>(qkv_w, Wq, C3);
  gemm_k<0><<<dim3(64, 5), 256, 0, stream>>>(A, Wc, conv_b, tokens, nullptr, nullptr, nullptr);
  gemm_k<1><<<dim3(64, 14), 256, 0, stream>>>(tokens, Wq, qkv_b, nullptr, qbuf, kbuf, vbuf);
  vtrans_k<<<dim3(112, 16), 256, 0, stream>>>(vbuf, vTb);
  attn_k<<<112 * 16, 256, 0, stream>>>(qbuf, kbuf, vTb, out);
}

// Round 2
// 193.357 us; speedup vs baseline: 1.0763x; 1.0763x over previous
//
#include <hip/hip_runtime.h>

typedef unsigned short u16;
typedef __attribute__((ext_vector_type(8))) short bf16x8;   // 8 bf16 (4 VGPRs)
typedef __attribute__((ext_vector_type(4))) float f32x4;    // MFMA C/D frag

#define MTOK 8192   // B*N tokens
#define KP   640    // K padded (588 -> 640 = 10*64)
#define CC   588
#define C3   1764
#define NH   14
#define SEQ  1024
#define HD   42
#define DP   64     // head-dim padded for QK^T K-loop
#define DV   48     // V^T rows: 42 real + ones row (42) + zeros

static __device__ __forceinline__ u16 f2b(float f) {  // fp32 -> bf16 RNE
  unsigned u = __builtin_bit_cast(unsigned, f);
  u = (u + 0x7FFFu + ((u >> 16) & 1u)) >> 16;
  return (u16)u;
}

static __device__ __forceinline__ void gl_lds16(const void* g, void* l) {
  // async global->LDS, 16B/lane; LDS dst is wave-uniform base + lane*16
  auto gp = (const unsigned int __attribute__((address_space(1)))*)((unsigned long long)g);
  auto lp = (unsigned int __attribute__((address_space(3)))*)((unsigned long long)l);
  __builtin_amdgcn_global_load_lds(gp, lp, 16, 0, 0);
}

// ---------------- im2col: x [8,3,448,448] f32 -> A [8192][640] bf16 (zero-padded) ----------------
__global__ void im2col_k(const float* __restrict__ x, u16* __restrict__ A) {
  int t = blockIdx.x;
  int b = t >> 10, pi = t & 1023, ph = pi >> 5, pw = pi & 31;
  const float* xb = x + (size_t)b * 3 * 448 * 448;
  for (int kk = threadIdx.x; kk < KP; kk += 256) {
    float v = 0.f;
    if (kk < CC) {
      int c = kk / 196, rem = kk - c * 196, i = rem / 14, j = rem - i * 14;
      v = xb[(size_t)(c * 448 + ph * 14 + i) * 448 + pw * 14 + j];
    }
    A[(size_t)t * KP + kk] = f2b(v);
  }
}

// ---------------- weight pad/convert: [R][588] f32 -> [Rp][640] bf16 (zeros elsewhere) ----------------
__global__ void padw_k(const float* __restrict__ w, u16* __restrict__ dst, int R) {
  int r = blockIdx.x;
  for (int c = threadIdx.x; c < KP; c += 256) {
    float v = (r < R && c < CC) ? w[(size_t)r * CC + c] : 0.f;
    dst[(size_t)r * KP + c] = f2b(v);
  }
}

// ---------------- 128x128x(BK=64) bf16 MFMA GEMM, C = A * Bt^T ----------------
template <int MODE>
__global__ void __launch_bounds__(256, 2) gemm_k(
    const u16* __restrict__ A, const u16* __restrict__ Bt,
    const float* __restrict__ bias, u16* __restrict__ out0,
    u16* __restrict__ qb, u16* __restrict__ kb, u16* __restrict__ vb) {
  __shared__ alignas(16) u16 sA[128 * 64];
  __shared__ alignas(16) u16 sB[128 * 64];
  const int tid = threadIdx.x;
  const int wave = tid >> 6, lane = tid & 63, quad = lane >> 4, l16 = lane & 15;
  const int wi = wave >> 1, wj = wave & 1;
  const int m0 = blockIdx.x * 128, n0 = blockIdx.y * 128;
  const int rL = lane >> 3, scid = lane & 7;
  const f32x4 z4 = {0.f, 0.f, 0.f, 0.f};

  f32x4 acc[4][4];
#pragma unroll
  for (int i = 0; i < 4; i++)
#pragma unroll
    for (int j = 0; j < 4; j++) acc[i][j] = z4;

  for (int k0 = 0; k0 < KP; k0 += 64) {
    __syncthreads();
#pragma unroll
    for (int cc = wave; cc < 16; cc += 4) {
      int r = cc * 8 + rL;
      int sch = scid ^ (r & 7);
      gl_lds16(A + ((size_t)(m0 + r) * KP + k0 + sch * 8), &sA[cc * 512]);
    }
#pragma unroll
    for (int cc = wave; cc < 16; cc += 4) {
      int r = cc * 8 + rL;
      int sch = scid ^ (r & 7);
      gl_lds16(Bt + ((size_t)(n0 + r) * KP + k0 + sch * 8), &sB[cc * 512]);
    }
    __syncthreads();
#pragma unroll
    for (int ks = 0; ks < 2; ks++) {
      bf16x8 af[4], bfr[4];
#pragma unroll
      for (int i = 0; i < 4; i++) {
        int r = wi * 64 + i * 16 + l16;
        int ch = (ks * 4 + quad) ^ (r & 7);
        af[i] = *(const bf16x8*)&sA[r * 64 + ch * 8];
      }
#pragma unroll
      for (int j = 0; j < 4; j++) {
        int r = wj * 64 + j * 16 + l16;
        int ch = (ks * 4 + quad) ^ (r & 7);
        bfr[j] = *(const bf16x8*)&sB[r * 64 + ch * 8];
      }
#pragma unroll
      for (int i = 0; i < 4; i++)
#pragma unroll
        for (int j = 0; j < 4; j++)
          acc[i][j] = __builtin_amdgcn_mfma_f32_16x16x32_bf16(af[i], bfr[j], acc[i][j], 0, 0, 0);
    }
  }

  const int baser = wi * 64 + quad * 4;  // C/D: col = lane&15, row = quad*4 + reg
  if (MODE == 0) {
#pragma unroll
    for (int j = 0; j < 4; j++) {
      int col = n0 + wj * 64 + j * 16 + l16;
      float bs = (col < CC) ? bias[col] : 0.f;
#pragma unroll
      for (int i = 0; i < 4; i++) {
        int row = m0 + baser + i * 16;
#pragma unroll
        for (int r = 0; r < 4; r++)
          out0[(size_t)(row + r) * KP + col] = f2b(acc[i][j][r] + bs);
      }
    }
  } else {
#pragma unroll
    for (int j = 0; j < 4; j++) {
      int col = n0 + wj * 64 + j * 16 + l16;
      if (col < C3) {
        float bs = bias[col];
        int which = col / CC;
        int rem = col - which * CC;
        int h = rem / HD;
        int d = rem - h * HD;
        u16* dst = (which == 0) ? qb : (which == 1) ? kb : vb;
#pragma unroll
        for (int i = 0; i < 4; i++) {
          int row = m0 + baser + i * 16;
#pragma unroll
          for (int r = 0; r < 4; r++) {
            int rw = row + r;
            int b = rw >> 10, n = rw & 1023;
            dst[((size_t)((b * NH + h) * SEQ + n)) * DP + d] = f2b(acc[i][j][r] + bs);
          }
        }
      }
    }
  }
}

// ---------------- V transpose: v [bh][n][64] -> vT [bh][48][1024]; row 42 = ones, 43..47 = 0 ----------------
__global__ void vtrans_k(const u16* __restrict__ vb, u16* __restrict__ vT) {
  __shared__ u16 tile[64 * 49];
  int bh = blockIdx.x, mt = blockIdx.y;
  for (int idx = threadIdx.x; idx < 64 * DV; idx += 256) {
    int n = idx / DV, d = idx - n * DV;
    u16 v = 0;
    if (d < HD) v = vb[((size_t)(bh * SEQ + mt * 64 + n)) * DP + d];
    tile[n * 49 + d] = v;
  }
  __syncthreads();
  for (int idx = threadIdx.x; idx < DV * 64; idx += 256) {
    int d = idx >> 6, n = idx & 63;
    u16 v = (d < HD) ? tile[n * 49 + d] : ((d == HD) ? (u16)0x3F80 : (u16)0);
    vT[((size_t)(bh * DV + d)) * SEQ + mt * 64 + n] = v;
  }
}

// ---------------- attention: 256-row Q-tile per block; 4 waves x 64 q-rows; flash over 16 KV tiles ----------------
__global__ void __launch_bounds__(256, 2) attn_k(
    const u16* __restrict__ qb, const u16* __restrict__ kb,
    const u16* __restrict__ vT, float* __restrict__ out) {
  __shared__ alignas(16) u16 sK[64 * 64];    // 8 KB swizzled
  __shared__ alignas(16) u16 sV[DV * 64];    // 6 KB swizzled V^T tile
  __shared__ alignas(16) u16 sP[256 * 72];   // 36 KB; per-wave private 64-row regions
  __shared__ float lbuf[256];
  const int tid = threadIdx.x;
  const int wave = tid >> 6, lane = tid & 63, quad = lane >> 4, l16 = lane & 15;
  // XCD swizzle: all 4 q-tiles of one bh land on the same XCD (blockIdx % 8 heuristic)
  const int g = blockIdx.x;
  const int bh = (g & 7) * 14 + (g >> 5);
  const int qt = (g >> 3) & 3;
  const int q0 = qt * 256;
  const int rL = lane >> 3, scid = lane & 7;
  const float SC2 = 0.18033688011112042f;  // 0.125 * log2(e)
  const f32x4 z4 = {0.f, 0.f, 0.f, 0.f};
  const int prow = wave * 64;

  bf16x8 aq[4][2];  // Q resident: wave owns rows q0+wave*64 .. +63
#pragma unroll
  for (int i = 0; i < 4; i++) {
    const u16* qrow = qb + ((size_t)(bh * SEQ + q0 + wave * 64 + i * 16 + l16)) * DP;
    aq[i][0] = *(const bf16x8*)&qrow[quad * 8];
    aq[i][1] = *(const bf16x8*)&qrow[32 + quad * 8];
  }
  f32x4 o[4][3];  // 64x48 accum; col 42 = row-sum (ones column of V^T)
#pragma unroll
  for (int i = 0; i < 4; i++)
#pragma unroll
    for (int j = 0; j < 3; j++) o[i][j] = z4;
  const u16* kb0 = kb + (size_t)bh * SEQ * DP;
  const u16* vb0 = vT + (size_t)bh * DV * SEQ;

  for (int kt = 0; kt < 16; kt++) {
    const int m0 = kt * 64;
    __syncthreads();  // prior iter's sK/sV reads done
    {
      const u16* ktile = kb0 + (size_t)m0 * DP;
#pragma unroll
      for (int cc = wave; cc < 8; cc += 4) {
        int r = cc * 8 + rL;
        gl_lds16(ktile + ((size_t)r * 64 + (scid ^ (r & 7)) * 8), &sK[cc * 512]);
      }
#pragma unroll
      for (int cc = wave; cc < 6; cc += 4) {
        int d = cc * 8 + rL;
        gl_lds16(vb0 + ((size_t)d * SEQ + m0 + (scid ^ (d & 7)) * 8), &sV[cc * 512]);
      }
    }
    __syncthreads();
    // K B-frags loaded once, shared across all 4 row-blocks
    bf16x8 bk[4][2];
#pragma unroll
    for (int j = 0; j < 4; j++) {
      int n = j * 16 + l16;
#pragma unroll
      for (int ks = 0; ks < 2; ks++)
        bk[j][ks] = *(const bf16x8*)&sK[n * 64 + (((ks * 4 + quad) ^ (n & 7)) * 8)];
    }
    // S = Q K^T ; P = exp2(S*c) -> private sP rows (intra-wave, no barrier needed)
#pragma unroll
    for (int i = 0; i < 4; i++) {
#pragma unroll
      for (int j = 0; j < 4; j++) {
        f32x4 s = z4;
        s = __builtin_amdgcn_mfma_f32_16x16x32_bf16(aq[i][0], bk[j][0], s, 0, 0, 0);
        s = __builtin_amdgcn_mfma_f32_16x16x32_bf16(aq[i][1], bk[j][1], s, 0, 0, 0);
#pragma unroll
        for (int r = 0; r < 4; r++)
          sP[(prow + i * 16 + quad * 4 + r) * 72 + j * 16 + l16] =
              f2b(__builtin_amdgcn_exp2f(s[r] * SC2));
      }
    }
    // O += P V
#pragma unroll
    for (int ks = 0; ks < 2; ks++) {
      bf16x8 bv[3];
#pragma unroll
      for (int j = 0; j < 3; j++) {
        int d = j * 16 + l16;
        bv[j] = *(const bf16x8*)&sV[d * 64 + (((ks * 4 + quad) ^ (d & 7)) * 8)];
      }
#pragma unroll
      for (int i = 0; i < 4; i++) {
        bf16x8 ap = *(const bf16x8*)&sP[(prow + i * 16 + l16) * 72 + ks * 32 + quad * 8];
#pragma unroll
        for (int j = 0; j < 3; j++)
          o[i][j] = __builtin_amdgcn_mfma_f32_16x16x32_bf16(ap, bv[j], o[i][j], 0, 0, 0);
      }
    }
  }
  // epilogue: row-sum lives in col 42 (j=2, l16==10); broadcast via LDS, normalize, store fp32
  __syncthreads();
  if (l16 == 10) {
#pragma unroll
    for (int i = 0; i < 4; i++)
#pragma unroll
      for (int r = 0; r < 4; r++)
        lbuf[prow + i * 16 + quad * 4 + r] = o[i][2][r];
  }
  __syncthreads();
  const int b = bh / NH, h = bh - b * NH;
#pragma unroll
  for (int i = 0; i < 4; i++) {
#pragma unroll
    for (int r = 0; r < 4; r++) {
      int row = prow + i * 16 + quad * 4 + r;
      float rc = 1.f / lbuf[row];
      float* orow = out + ((size_t)(b * SEQ + q0 + row)) * CC + h * HD;
#pragma unroll
      for (int j = 0; j < 3; j++) {
        int d = j * 16 + l16;
        if (d < HD) orow[d] = o[i][j][r] * rc;
      }
    }
  }
}

extern "C" void kernel_launch(void* const* d_in, const int* in_sizes, int n_in,
                              void* d_out, int out_size, void* d_ws, size_t ws_size,
                              hipStream_t stream) {
  (void)in_sizes; (void)n_in; (void)out_size; (void)ws_size;
  const float* x      = (const float*)d_in[0];
  const float* conv_w = (const float*)d_in[1];
  const float* conv_b = (const float*)d_in[2];
  const float* qkv_w  = (const float*)d_in[3];
  const float* qkv_b  = (const float*)d_in[4];
  float* out = (float*)d_out;

  char* ws = (char*)d_ws;
  size_t off = 0;
  u16* A      = (u16*)(ws + off); off += (size_t)MTOK * KP * 2;
  u16* Wc     = (u16*)(ws + off); off += (size_t)640 * KP * 2;
  u16* Wq     = (u16*)(ws + off); off += (size_t)1792 * KP * 2;
  u16* tokens = (u16*)(ws + off); off += (size_t)MTOK * KP * 2;
  u16* qbuf   = (u16*)(ws + off); off += (size_t)112 * SEQ * DP * 2;
  u16* kbuf   = (u16*)(ws + off); off += (size_t)112 * SEQ * DP * 2;
  u16* vbuf   = (u16*)(ws + off); off += (size_t)112 * SEQ * DP * 2;
  u16* vTb    = (u16*)(ws + off); off += (size_t)112 * DV * SEQ * 2;

  // only kbuf pads must be zero: Q-pad (poison, finite) x K-pad (0) = 0 in QK^T
  hipMemsetAsync(kbuf, 0, (size_t)112 * SEQ * DP * 2, stream);
  im2col_k<<<MTOK, 256, 0, stream>>>(x, A);
  padw_k<<<640, 256, 0, stream>>>(conv_w, Wc, CC);
  padw_k<<<1792, 256, 0, stream>>>(qkv_w, Wq, C3);
  gemm_k<0><<<dim3(64, 5), 256, 0, stream>>>(A, Wc, conv_b, tokens, nullptr, nullptr, nullptr);
  gemm_k<1><<<dim3(64, 14), 256, 0, stream>>>(tokens, Wq, qkv_b, nullptr, qbuf, kbuf, vbuf);
  vtrans_k<<<dim3(112, 16), 256, 0, stream>>>(vbuf, vTb);
  attn_k<<<448, 256, 0, stream>>>(qbuf, kbuf, vTb, out);
}